// Round 8
// baseline (381.372 us; speedup 1.0000x reference)
//
#include <hip/hip_runtime.h>

typedef _Float16 half8  __attribute__((ext_vector_type(8)));
typedef _Float16 half4v __attribute__((ext_vector_type(4)));
typedef _Float16 half2v __attribute__((ext_vector_type(2)));
typedef float    f32x4  __attribute__((ext_vector_type(4)));
typedef float    f32x2  __attribute__((ext_vector_type(2)));
typedef int      i32x4  __attribute__((ext_vector_type(4)));

#define NB 2
#define N_C 16384
#define N_F 65536
#define E_C 65536
#define E_F 262144

#define INV4  ((size_t)N_F / 4)                    // 16,384
#define CNT4  ((size_t)(N_F + N_C) / 4)            // 20,480

// LDS-only barrier: waits LDS ops, does NOT drain vmcnt (keeps global prefetch in flight).
__device__ __forceinline__ void lds_barrier() {
    asm volatile("s_waitcnt lgkmcnt(0)" ::: "memory");
    __builtin_amdgcn_s_barrier();
    __builtin_amdgcn_sched_barrier(0);
}

// ---------------- small clear: inv=-1, cnt=0 ----------------
__global__ void clear_small(int* __restrict__ inv, int* __restrict__ cnt) {
    size_t i = (size_t)blockIdx.x * 256 + threadIdx.x;
    const i32x4 z = {0, 0, 0, 0};
    const i32x4 m1 = {-1, -1, -1, -1};
    if (i < INV4) ((i32x4*)inv)[i] = m1;
    else if (i < INV4 + CNT4) ((i32x4*)cnt)[i - INV4] = z;
}

// ---------------- weight swizzles ----------------
__device__ inline void swizzle_dev(const float* __restrict__ W, _Float16* __restrict__ Ws,
                                   int N, int o) {
    int j = o & 7;
    int lane = (o >> 3) & 63;
    int frag = o >> 9;
    int ntiles = N >> 4;
    int nt = frag % ntiles;
    int kt = frag / ntiles;
    int k = kt * 32 + (lane >> 4) * 8 + j;
    int n = nt * 16 + (lane & 15);
    Ws[o] = (_Float16)W[k * N + n];
}

__device__ inline void swz_node(const float* __restrict__ W, _Float16* __restrict__ Ws,
                                int CIN, int COUT, int o) {
    int j = o & 7;
    int lane = (o >> 3) & 63;
    int frag = o >> 9;
    int N2 = 2 * COUT;
    int ntiles = N2 >> 4;
    int nt = frag % ntiles;
    int kt = frag / ntiles;
    int k = kt * 32 + (lane >> 4) * 8 + j;
    int n = nt * 16 + (lane & 15);
    float v = (n < COUT) ? W[k * COUT + n] - W[(k + CIN) * COUT + n]
                         : W[(k + CIN) * COUT + (n - COUT)];
    Ws[o] = (_Float16)v;
}

// block ranges: [0,64) inv | [64,192) sW1n | [192,256) sW2 | [256,320) aW1n
//               [320,336) aW2 | [336,400) bW1n | [400,464) bW2 | [464,466) b1h
//               [466,1490) hist_f | [1490,1746) hist_c
__global__ void setup_all(const int* __restrict__ idx, int* __restrict__ inv,
                          const float* sW1, const float* sW2, const float* aW1,
                          const float* aW2, const float* bW1, const float* bW2,
                          const float* sb1, const float* ab1, const float* bb1,
                          _Float16* sW1n, _Float16* sW2s, _Float16* aW1n,
                          _Float16* aW2s, _Float16* bW1n, _Float16* bW2s,
                          _Float16* b1h,
                          const int* __restrict__ ei_f, const int* __restrict__ ei_c,
                          int* __restrict__ cnt) {
    const int bb = blockIdx.x, t = threadIdx.x;
    if (bb < 64) {
        int i = bb * 256 + t;
        inv[idx[i]] = i;
    } else if (bb < 192) {
        swz_node(sW1, sW1n, 128, 128, (bb - 64) * 256 + t);
    } else if (bb < 256) {
        swizzle_dev(sW2, sW2s, 128, (bb - 192) * 256 + t);
    } else if (bb < 320) {
        swz_node(aW1, aW1n, 128, 64, (bb - 256) * 256 + t);
    } else if (bb < 336) {
        swizzle_dev(aW2, aW2s, 64, (bb - 320) * 256 + t);
    } else if (bb < 400) {
        swz_node(bW1, bW1n, 64, 128, (bb - 336) * 256 + t);
    } else if (bb < 464) {
        swizzle_dev(bW2, bW2s, 128, (bb - 400) * 256 + t);
    } else if (bb < 466) {
        int i = (bb - 464) * 256 + t;
        if (i < 128) b1h[i] = (_Float16)sb1[i];
        else if (i < 192) b1h[i] = (_Float16)ab1[i - 128];
        else if (i < 320) b1h[i] = (_Float16)bb1[i - 192];
    } else if (bb < 1490) {
        int e = (bb - 466) * 256 + t;
        atomicAdd(&cnt[ei_f[E_F + e]], 1);
    } else {
        int e = (bb - 1490) * 256 + t;
        atomicAdd(&cnt[N_F + ei_c[E_C + e]], 1);
    }
}

// ---------------- counting sort ----------------
__global__ void scan1(const int* __restrict__ cnt, int* __restrict__ csum) {
    __shared__ int red[4];
    int v = cnt[blockIdx.x * 256 + threadIdx.x];
    #pragma unroll
    for (int off = 32; off >= 1; off >>= 1) v += __shfl_xor(v, off, 64);
    if ((threadIdx.x & 63) == 0) red[threadIdx.x >> 6] = v;
    __syncthreads();
    if (threadIdx.x == 0) csum[blockIdx.x] = red[0] + red[1] + red[2] + red[3];
}

// scan3 + inline block-base (replaces scan2) + selective zero + flag
// f-rows: 32-aligned windows (dual scatters in 32-row windows)
// c-rows: 16-aligned windows (COUT=64 kernel)
__global__ void scan3zf(const int* __restrict__ cnt, const int* __restrict__ csum,
                        int* __restrict__ cursor, unsigned char* __restrict__ flagF,
                        float* __restrict__ out, float* __restrict__ h_a) {
    __shared__ int buf[256];
    __shared__ int red[4];
    const int t = threadIdx.x, bb = blockIdx.x;

    const int lo = (bb < 256) ? 0 : 256;
    int part = 0;
    for (int j = lo + t; j < bb; j += 256) part += csum[j];
    #pragma unroll
    for (int off = 32; off >= 1; off >>= 1) part += __shfl_xor(part, off, 64);
    if ((t & 63) == 0) red[t >> 6] = part;

    const int d = bb * 256 + t;
    int v = cnt[d];
    buf[t] = v;
    __syncthreads();
    const int base = red[0] + red[1] + red[2] + red[3];
    for (int off = 1; off < 256; off <<= 1) {
        int u = (t >= off) ? buf[t - off] : 0;
        __syncthreads();
        buf[t] += u;
        __syncthreads();
    }
    const int start = base + buf[t] - v;
    cursor[d] = start;
    const int deg = v;
    const int end = start + deg;
    const f32x4 z = {0.f, 0.f, 0.f, 0.f};
    if (d < N_F) {
        const bool pred = (deg == 0) || ((start >> 5) != ((end - 1) >> 5));
        flagF[d] = pred ? 1 : 0;
        if (pred) {
            f32x4* r0 = (f32x4*)(out + (size_t)d * 128);
            f32x4* r1 = (f32x4*)(out + ((size_t)N_F + d) * 128);
            #pragma unroll
            for (int i = 0; i < 32; ++i) { r0[i] = z; r1[i] = z; }
        }
    } else {
        const int dc = d - N_F;
        const bool pred = (deg == 0) || ((start >> 4) != ((end - 1) >> 4));
        if (pred) {
            f32x4* r0 = (f32x4*)(h_a + (size_t)dc * 64);
            f32x4* r1 = (f32x4*)(h_a + ((size_t)N_C + dc) * 64);
            #pragma unroll
            for (int i = 0; i < 16; ++i) { r0[i] = z; r1[i] = z; }
        }
    }
}

// ---------------- node-level GEMM1 body: P[node] = [ x@(W1t-W1b)+b1 | x@W1b ] (fp16) ----------------
template <int CIN, int COUT>
__device__ void node_gemm_body(const float* __restrict__ x, const _Float16* __restrict__ W1n,
                               const float* __restrict__ b1, _Float16* __restrict__ P,
                               _Float16* L, int blk, int t) {
    constexpr int N2 = 2 * COUT;
    constexpr int FP = CIN + 8;
    constexpr int P2 = N2 + 8;
    constexpr int NPW = N2 / 4;
    constexpr int NT = NPW / 16;

    const size_t r0 = (size_t)blk * 64;

    {
        const int m = t >> 2, l4 = t & 3;
        const float* src = x + (r0 + m) * CIN + l4 * (CIN / 4);
        #pragma unroll
        for (int i = 0; i < CIN / 16; ++i) {
            f32x4 v = *(const f32x4*)(src + i * 4);
            half4v h;
            #pragma unroll
            for (int c = 0; c < 4; ++c) h[c] = (_Float16)v[c];
            *(half4v*)(L + m * FP + l4 * (CIN / 4) + i * 4) = h;
        }
    }
    __syncthreads();

    const int wv = t >> 6, lane = t & 63;
    const int q = lane >> 4, lm = lane & 15;
    const int n0 = wv * NPW;
    const f32x4 zero4 = {0.f, 0.f, 0.f, 0.f};

    f32x4 acc[4][NT];
    #pragma unroll
    for (int mt = 0; mt < 4; ++mt)
        #pragma unroll
        for (int nt = 0; nt < NT; ++nt) acc[mt][nt] = zero4;

    __builtin_amdgcn_s_setprio(1);
    #pragma unroll
    for (int kt = 0; kt < CIN / 32; ++kt) {
        half8 a[4];
        #pragma unroll
        for (int mt = 0; mt < 4; ++mt)
            a[mt] = *(const half8*)(L + (mt * 16 + lm) * FP + kt * 32 + q * 8);
        #pragma unroll
        for (int nt = 0; nt < NT; ++nt) {
            half8 bf = *(const half8*)(W1n + ((size_t)(kt * (N2 / 16) + wv * NT + nt) * 64 + lane) * 8);
            #pragma unroll
            for (int mt = 0; mt < 4; ++mt)
                acc[mt][nt] = __builtin_amdgcn_mfma_f32_16x16x32_f16(a[mt], bf, acc[mt][nt], 0, 0, 0);
        }
    }
    __builtin_amdgcn_s_setprio(0);
    __syncthreads();

    #pragma unroll
    for (int nt = 0; nt < NT; ++nt) {
        const int col = n0 + nt * 16 + lm;
        const float bv = (col < COUT) ? b1[col] : 0.f;
        #pragma unroll
        for (int mt = 0; mt < 4; ++mt)
            #pragma unroll
            for (int r = 0; r < 4; ++r)
                L[(mt * 16 + q * 4 + r) * P2 + col] = (_Float16)(acc[mt][nt][r] + bv);
    }
    __syncthreads();

    constexpr int CH = 64 * N2 / 8;
    for (int i = t; i < CH; i += 256) {
        int row = i / (N2 / 8), c8 = i % (N2 / 8);
        *(half8*)(P + (r0 + row) * N2 + c8 * 8) = *(const half8*)(L + row * P2 + c8 * 8);
    }
}

// ---------------- merged: edge scatter (+einfo) and s/a node GEMMs ----------------
__launch_bounds__(256, 4) __global__
void scatter_nodesa(const int* __restrict__ ei_f, const int* __restrict__ ei_c,
                    const int* __restrict__ inv, int* __restrict__ cursor,
                    i32x4* __restrict__ ef_info, i32x4* __restrict__ ec_info,
                    const float* __restrict__ x,
                    const _Float16* __restrict__ sW1n, const float* __restrict__ sb1,
                    _Float16* __restrict__ Ps,
                    const _Float16* __restrict__ aW1n, const float* __restrict__ ab1,
                    _Float16* __restrict__ Pa) {
    __shared__ __align__(16) _Float16 L[16896];
    const int bb = blockIdx.x, t = threadIdx.x;
    if (bb < 1024) {
        int e = bb * 256 + t;
        int s_ = ei_f[e];
        int d_ = ei_f[E_F + e];
        int p = atomicAdd(&cursor[d_], 1);
        i32x4 rec;
        rec.x = inv[s_]; rec.y = inv[d_]; rec.z = d_; rec.w = 0;
        ef_info[p] = rec;
    } else if (bb < 1280) {
        int e = (bb - 1024) * 256 + t;
        int s_ = ei_c[e];
        int d_ = ei_c[E_C + e];
        int p = atomicAdd(&cursor[N_F + d_], 1);
        i32x4 rec;
        rec.x = s_; rec.y = d_; rec.z = d_; rec.w = 0;
        ec_info[p] = rec;
    } else if (bb < 1280 + NB * N_C / 64) {
        node_gemm_body<128, 128>(x, sW1n, sb1, Ps, L, bb - 1280, t);
    } else {
        node_gemm_body<128, 64>(x, aW1n, ab1, Pa, L, bb - 1280 - NB * N_C / 64, t);
    }
}

// standalone node GEMM for the b conv (depends on h_a)
template <int CIN, int COUT>
__launch_bounds__(256, 4) __global__
void node_gemm(const float* __restrict__ x, const _Float16* __restrict__ W1n,
               const float* __restrict__ b1, _Float16* __restrict__ P) {
    __shared__ __align__(16) _Float16 L[16896];
    node_gemm_body<CIN, COUT>(x, W1n, b1, P, L, blockIdx.x, threadIdx.x);
}

__device__ inline half8 relu8(half8 h) {
#if __has_builtin(__builtin_elementwise_max)
    half8 z = {};
    return __builtin_elementwise_max(h, z);
#else
    #pragma unroll
    for (int i = 0; i < 8; ++i) h[i] = h[i] > (_Float16)0 ? h[i] : (_Float16)0;
    return h;
#endif
}

// ---------------- single edgeconv (stage 8, COUT=64) ----------------
template <int COUT, bool FRESH>
__launch_bounds__(256, 8) __global__
void edge2_mfma(const _Float16* __restrict__ P, int ps,
                const i32x4* __restrict__ einfo, int E,
                const _Float16* __restrict__ W2s, const float* __restrict__ b2,
                const float* __restrict__ g, const float* __restrict__ bt,
                const _Float16* __restrict__ b1h,
                float* __restrict__ dest, int bs_out) {
    constexpr int HPITCH = COUT + 8;
    constexpr int NPW = COUT / 4;
    constexpr int NT = NPW / 16;

    __shared__ __align__(16) _Float16 region[64 * HPITCH];
    __shared__ int dstl[64];
    __shared__ int dpnL[2];
    __shared__ float muL[64];
    __shared__ float rsL[64];

    _Float16* h1L = region;
    _Float16* vnL = region;

    const int t = threadIdx.x;
    const int eb = blockIdx.x * 64;
    const int b = eb / E;
    const int e0 = eb - b * E;

    {
        if (t == 0) dpnL[0] = (e0 > 0) ? einfo[e0 - 1].z : -2;
        else if (t == 1) dpnL[1] = (e0 + 64 < E) ? einfo[e0 + 64].z : -2;
        const int m = t >> 2, l4 = t & 3;
        const i32x4 rec = einfo[e0 + m];
        const int si = rec.x, di = rec.y;
        if (l4 == 0) dstl[m] = rec.z;
        const _Float16* pb = P + (size_t)b * ps;
        const _Float16* ub = (di >= 0) ? pb + (size_t)di * (2 * COUT) : b1h;
        const _Float16* vb = pb + (size_t)(si >= 0 ? si : 0) * (2 * COUT) + COUT;
        constexpr int CPT = COUT / 4;
        const int c0 = l4 * CPT;
        #pragma unroll
        for (int i = 0; i < CPT / 8; ++i) {
            half8 u = *(const half8*)(ub + c0 + i * 8);
            half8 v = {};
            if (si >= 0) v = *(const half8*)(vb + c0 + i * 8);
            *(half8*)(h1L + m * HPITCH + c0 + i * 8) = relu8(u + v);
        }
    }
    __syncthreads();  // B1

    const int wv = t >> 6, lane = t & 63;
    const int q = lane >> 4, lm = lane & 15;
    const int n0 = wv * NPW;
    const f32x4 zero4 = {0.f, 0.f, 0.f, 0.f};

    f32x4 acc[4][NT];
    #pragma unroll
    for (int mt = 0; mt < 4; ++mt)
        #pragma unroll
        for (int nt = 0; nt < NT; ++nt) acc[mt][nt] = zero4;

    __builtin_amdgcn_s_setprio(1);
    #pragma unroll
    for (int kt = 0; kt < COUT / 32; ++kt) {
        half8 a[4];
        #pragma unroll
        for (int mt = 0; mt < 4; ++mt)
            a[mt] = *(const half8*)(h1L + (mt * 16 + lm) * HPITCH + kt * 32 + q * 8);
        #pragma unroll
        for (int nt = 0; nt < NT; ++nt) {
            half8 bf = *(const half8*)(W2s + ((size_t)(kt * (COUT / 16) + wv * NT + nt) * 64 + lane) * 8);
            #pragma unroll
            for (int mt = 0; mt < 4; ++mt)
                acc[mt][nt] = __builtin_amdgcn_mfma_f32_16x16x32_f16(a[mt], bf, acc[mt][nt], 0, 0, 0);
        }
    }
    __builtin_amdgcn_s_setprio(0);
    __syncthreads();  // B2

    #pragma unroll
    for (int nt = 0; nt < NT; ++nt) {
        const float b2v = b2[n0 + nt * 16 + lm];
        #pragma unroll
        for (int mt = 0; mt < 4; ++mt)
            #pragma unroll
            for (int r = 0; r < 4; ++r)
                vnL[(mt * 16 + q * 4 + r) * HPITCH + n0 + nt * 16 + lm] =
                    (_Float16)(acc[mt][nt][r] + b2v);
    }
    __syncthreads();  // B3

    {
        const int m = t >> 2, p = t & 3;
        constexpr int CPT = COUT / 4;
        float s = 0.f, s2 = 0.f;
        #pragma unroll
        for (int c = 0; c < CPT / 8; ++c) {
            half8 h8 = *(const half8*)(vnL + m * HPITCH + p * CPT + c * 8);
            #pragma unroll
            for (int j = 0; j < 8; ++j) {
                float v = (float)h8[j];
                s += v;
                s2 += v * v;
            }
        }
        s += __shfl_xor(s, 1, 64);  s2 += __shfl_xor(s2, 1, 64);
        s += __shfl_xor(s, 2, 64);  s2 += __shfl_xor(s2, 2, 64);
        if (p == 0) {
            float mu = s * (1.f / COUT);
            muL[m] = mu;
            rsL[m] = rsqrtf(s2 * (1.f / COUT) - mu * mu + 1e-5f);
        }
    }
    __syncthreads();  // B4

    {
        constexpr int CG = COUT / 64;
        constexpr int W  = 4 / CG;
        constexpr int RW = 64 / W;
        const int wv2 = t >> 6, l2 = t & 63;
        const int cg = wv2 % CG;
        const int h  = wv2 / CG;
        const int c  = cg * 64 + l2;
        const int r0 = h * RW;
        const float gv = g[c], bv = bt[c];
        float* const ob = dest + (size_t)b * bs_out + c;
        int dcur = dstl[r0];
        const int dprev = (r0 == 0) ? dpnL[0] : dstl[r0 - 1];
        bool bflag = (dcur == dprev);
        float rs = 0.f;
        #pragma unroll
        for (int i = 0; i < RW; ++i) {
            const int m = r0 + i;
            const float v = (float)vnL[m * HPITCH + c];
            rs += (v - muL[m]) * rsL[m] * gv + bv;
            const int dnxt = (i == RW - 1)
                               ? ((r0 + RW == 64) ? dpnL[1] : dstl[r0 + RW])
                               : dstl[m + 1];
            if (dnxt != dcur) {
                if (!FRESH || bflag) atomicAdd(ob + (size_t)dcur * COUT, rs);
                else ob[(size_t)dcur * COUT] = rs;
                rs = 0.f; dcur = dnxt; bflag = false;
            } else if (i == RW - 1) {
                atomicAdd(ob + (size_t)dcur * COUT, rs);
            }
        }
    }
}

// ---------------- fused dual edgeconv, 2-tile pipelined (stages 7+9, COUT=128, E=E_F) ----------------
// Block = 128 edges = 2 tiles of 64. T1's V rows are prefetched into registers during T0's
// gather and consumed after T0's full phase chain; lds_barrier() never drains vmcnt.
__launch_bounds__(256, 4) __global__
void edge2_dual(const _Float16* __restrict__ Ps, const _Float16* __restrict__ Pb,
                const i32x4* __restrict__ einfo,
                const _Float16* __restrict__ W2sS, const float* __restrict__ b2s,
                const float* __restrict__ gS, const float* __restrict__ btS,
                const _Float16* __restrict__ W2sB, const float* __restrict__ b2b,
                const float* __restrict__ gB, const float* __restrict__ btB,
                const _Float16* __restrict__ b1hS, const _Float16* __restrict__ b1hB,
                float* __restrict__ out) {
    constexpr int E = E_F;
    constexpr int HP = 136;   // h1 pitch (halfs)
    constexpr int IP = 264;   // interleaved vn pitch (halfs)

    __shared__ __align__(16) _Float16 region[2 * 64 * HP];
    __shared__ int dstl[128];     // dsts for both tiles
    __shared__ int dpnE[2];       // dst of edge e0-1, dst of edge e0+128
    __shared__ f32x4 stat4[64];   // {rsS, -muS*rsS, rsB, -muB*rsB}

    _Float16* const h1S = region;
    _Float16* const h1B = region + 64 * HP;
    _Float16* const vnI = region;

    const int t = threadIdx.x;
    const int eb = blockIdx.x * 128;
    const int b = eb / E;
    const int e0 = eb - b * E;

    const int gm = t >> 2, gl4 = t & 3;
    const int gc0 = gl4 * 32;
    const size_t pofs = (size_t)b * ((size_t)N_C * 256);

    const int wv = t >> 6, lane = t & 63;
    const int q = lane >> 4, lm = lane & 15;
    const int n0 = wv * 32;

    // ---- phase chain body for one tile (h1 already in LDS) ----
    auto run_tile = [&](int dOff, int dPrev, int dNext) {
        const f32x4 zero4 = {0.f, 0.f, 0.f, 0.f};
        f32x4 accS[4][2], accB[4][2];
        #pragma unroll
        for (int mt = 0; mt < 4; ++mt)
            #pragma unroll
            for (int nt = 0; nt < 2; ++nt) { accS[mt][nt] = zero4; accB[mt][nt] = zero4; }

        __builtin_amdgcn_s_setprio(1);
        #pragma unroll
        for (int kt = 0; kt < 4; ++kt) {
            half8 aS[4], aB[4];
            #pragma unroll
            for (int mt = 0; mt < 4; ++mt) {
                aS[mt] = *(const half8*)(h1S + (mt * 16 + lm) * HP + kt * 32 + q * 8);
                aB[mt] = *(const half8*)(h1B + (mt * 16 + lm) * HP + kt * 32 + q * 8);
            }
            #pragma unroll
            for (int nt = 0; nt < 2; ++nt) {
                half8 bS = *(const half8*)(W2sS + ((size_t)(kt * 8 + wv * 2 + nt) * 64 + lane) * 8);
                half8 bB = *(const half8*)(W2sB + ((size_t)(kt * 8 + wv * 2 + nt) * 64 + lane) * 8);
                #pragma unroll
                for (int mt = 0; mt < 4; ++mt) {
                    accS[mt][nt] = __builtin_amdgcn_mfma_f32_16x16x32_f16(aS[mt], bS, accS[mt][nt], 0, 0, 0);
                    accB[mt][nt] = __builtin_amdgcn_mfma_f32_16x16x32_f16(aB[mt], bB, accB[mt][nt], 0, 0, 0);
                }
            }
        }
        __builtin_amdgcn_s_setprio(0);
        lds_barrier();  // all h1 reads done -> overwrite region with vn

        #pragma unroll
        for (int nt = 0; nt < 2; ++nt) {
            const int col = n0 + nt * 16 + lm;
            const float b2vS = b2s[col];
            const float b2vB = b2b[col];
            #pragma unroll
            for (int mt = 0; mt < 4; ++mt)
                #pragma unroll
                for (int r = 0; r < 4; ++r) {
                    const int row = mt * 16 + q * 4 + r;
                    half2v pk;
                    pk[0] = (_Float16)(accS[mt][nt][r] + b2vS);
                    pk[1] = (_Float16)(accB[mt][nt][r] + b2vB);
                    *(half2v*)(vnI + row * IP + col * 2) = pk;
                }
        }
        lds_barrier();  // vn ready

        {
            const int m = t >> 2, p = t & 3;
            float sS = 0.f, s2S = 0.f, sB = 0.f, s2B = 0.f;
            #pragma unroll
            for (int k = 0; k < 8; ++k) {
                half8 h8 = *(const half8*)(vnI + m * IP + p * 64 + k * 8);
                #pragma unroll
                for (int j = 0; j < 8; j += 2) {
                    float a = (float)h8[j];     sS += a; s2S += a * a;
                    float c = (float)h8[j + 1]; sB += c; s2B += c * c;
                }
            }
            sS += __shfl_xor(sS, 1, 64);  s2S += __shfl_xor(s2S, 1, 64);
            sS += __shfl_xor(sS, 2, 64);  s2S += __shfl_xor(s2S, 2, 64);
            sB += __shfl_xor(sB, 1, 64);  s2B += __shfl_xor(s2B, 1, 64);
            sB += __shfl_xor(sB, 2, 64);  s2B += __shfl_xor(s2B, 2, 64);
            if (p == 0) {
                const float mS = sS * (1.f / 128.f);
                const float rS = rsqrtf(s2S * (1.f / 128.f) - mS * mS + 1e-5f);
                const float mB = sB * (1.f / 128.f);
                const float rB = rsqrtf(s2B * (1.f / 128.f) - mB * mB + 1e-5f);
                f32x4 st;
                st[0] = rS; st[1] = -mS * rS; st[2] = rB; st[3] = -mB * rB;
                stat4[m] = st;
            }
        }
        lds_barrier();  // stats ready

        {
            const int wv2 = t >> 6, l2 = t & 63;
            const int cg = wv2 & 1;
            const int h  = wv2 >> 1;
            const int c  = cg * 64 + l2;
            const int r0 = h * 32;
            const float gS_ = gS[c], gB_ = gB[c];
            const float bsum = btS[c] + btB[c];
            float* const ob = out + (size_t)b * ((size_t)N_F * 128) + c;
            int dcur = dstl[dOff + r0];
            const int dprev = (r0 == 0) ? dPrev : dstl[dOff + r0 - 1];
            bool bflag = (dcur == dprev);
            float rs = 0.f;
            #pragma unroll
            for (int i = 0; i < 32; ++i) {
                const int m = r0 + i;
                const half2v v2 = *(const half2v*)(vnI + m * IP + c * 2);
                const f32x4 st = stat4[m];
                rs += fmaf((float)v2[0], st[0], st[1]) * gS_
                    + fmaf((float)v2[1], st[2], st[3]) * gB_ + bsum;
                const int dnxt = (i == 31)
                                   ? ((r0 + 32 == 64) ? dNext : dstl[dOff + r0 + 32])
                                   : dstl[dOff + m + 1];
                if (dnxt != dcur) {
                    if (bflag) {
                        atomicAdd(ob + (size_t)dcur * 128, rs);
                    } else {
                        float v = rs > 0.f ? rs : 0.01f * rs;  // leaky: single writer
                        ob[(size_t)dcur * 128] = v;
                    }
                    rs = 0.f; dcur = dnxt; bflag = false;
                } else if (i == 31) {
                    atomicAdd(ob + (size_t)dcur * 128, rs);
                }
            }
        }
    };

    // ---- phase 0: T0 gather (+ T1 records, T1 V-row register prefetch) ----
    half8 pvS[4], pvB[4];
    int si1, di1;
    {
        if (t == 0) dpnE[0] = (e0 > 0) ? einfo[e0 - 1].z : -2;
        else if (t == 1) dpnE[1] = (e0 + 128 < E) ? einfo[e0 + 128].z : -2;
        const i32x4 rec0 = einfo[e0 + gm];
        const i32x4 rec1 = einfo[e0 + 64 + gm];
        si1 = rec1.x; di1 = rec1.y;
        if (gl4 == 0) { dstl[gm] = rec0.z; dstl[64 + gm] = rec1.z; }
        const int si = rec0.x, di = rec0.y;
        const _Float16* ubS = (di >= 0) ? Ps + pofs + (size_t)di * 256 : b1hS;
        const _Float16* ubB = (di >= 0) ? Pb + pofs + (size_t)di * 256 : b1hB;
        const size_t so = (size_t)(si >= 0 ? si : 0) * 256 + 128;
        const _Float16* vbS = Ps + pofs + so;
        const _Float16* vbB = Pb + pofs + so;
        #pragma unroll
        for (int i = 0; i < 4; ++i) {
            half8 uS = *(const half8*)(ubS + gc0 + i * 8);
            half8 uB = *(const half8*)(ubB + gc0 + i * 8);
            half8 vS = {}, vB = {};
            if (si >= 0) {
                vS = *(const half8*)(vbS + gc0 + i * 8);
                vB = *(const half8*)(vbB + gc0 + i * 8);
            }
            *(half8*)(h1S + gm * HP + gc0 + i * 8) = relu8(uS + vS);
            *(half8*)(h1B + gm * HP + gc0 + i * 8) = relu8(uB + vB);
        }
        // T1 V prefetch: issued now, consumed after T0's full phase chain
        const size_t so1 = (size_t)(si1 >= 0 ? si1 : 0) * 256 + 128;
        const _Float16* vbS1 = Ps + pofs + so1;
        const _Float16* vbB1 = Pb + pofs + so1;
        #pragma unroll
        for (int i = 0; i < 4; ++i) {
            pvS[i] = *(const half8*)(vbS1 + gc0 + i * 8);
            pvB[i] = *(const half8*)(vbB1 + gc0 + i * 8);
        }
    }
    lds_barrier();  // h1 T0 + dstl + dpnE ready (vmcnt NOT drained -> prefetch in flight)

    const int dNext0 = dstl[64];   // first dst of T1
    const int dPrev1 = dstl[63];   // last dst of T0
    run_tile(0, dpnE[0], dNext0);

    lds_barrier();  // all vn T0 reads done -> T1 may overwrite region

    // ---- T1 gather-write: fresh U loads + prefetched V regs ----
    {
        const _Float16* ubS = (di1 >= 0) ? Ps + pofs + (size_t)di1 * 256 : b1hS;
        const _Float16* ubB = (di1 >= 0) ? Pb + pofs + (size_t)di1 * 256 : b1hB;
        #pragma unroll
        for (int i = 0; i < 4; ++i) {
            half8 uS = *(const half8*)(ubS + gc0 + i * 8);
            half8 uB = *(const half8*)(ubB + gc0 + i * 8);
            half8 vS = {}, vB = {};
            if (si1 >= 0) { vS = pvS[i]; vB = pvB[i]; }
            *(half8*)(h1S + gm * HP + gc0 + i * 8) = relu8(uS + vS);
            *(half8*)(h1B + gm * HP + gc0 + i * 8) = relu8(uB + vB);
        }
    }
    lds_barrier();  // h1 T1 ready

    run_tile(64, dPrev1, dpnE[1]);
}

// ---------------- fixup: leaky for flagged rows only ----------------
__global__ void leaky_fix(float* __restrict__ out, const unsigned char* __restrict__ flagF) {
    const size_t i = (size_t)blockIdx.x * 256 + threadIdx.x;
    if (i >= (size_t)NB * N_F * 32) return;
    const int d = (int)((i >> 5) & (N_F - 1));
    if (!flagF[d]) return;
    f32x4 v = ((f32x4*)out)[i];
    #pragma unroll
    for (int c = 0; c < 4; ++c) v[c] = v[c] > 0.f ? v[c] : 0.01f * v[c];
    ((f32x4*)out)[i] = v;
}

extern "C" void kernel_launch(void* const* d_in, const int* in_sizes, int n_in,
                              void* d_out, int out_size, void* d_ws, size_t ws_size,
                              hipStream_t stream) {
    const float* x    = (const float*)d_in[0];
    const int*   idx  = (const int*)d_in[1];
    const int*   ei_c = (const int*)d_in[2];
    const int*   ei_f = (const int*)d_in[3];
    const float* sW1 = (const float*)d_in[4];
    const float* sb1 = (const float*)d_in[5];
    const float* sW2 = (const float*)d_in[6];
    const float* sb2 = (const float*)d_in[7];
    const float* sg  = (const float*)d_in[8];
    const float* sbt = (const float*)d_in[9];
    const float* aW1 = (const float*)d_in[10];
    const float* ab1 = (const float*)d_in[11];
    const float* aW2 = (const float*)d_in[12];
    const float* ab2 = (const float*)d_in[13];
    const float* ag  = (const float*)d_in[14];
    const float* abt = (const float*)d_in[15];
    const float* bW1 = (const float*)d_in[16];
    const float* bb1 = (const float*)d_in[17];
    const float* bW2 = (const float*)d_in[18];
    const float* bb2 = (const float*)d_in[19];
    const float* bg  = (const float*)d_in[20];
    const float* bbt = (const float*)d_in[21];

    float* out = (float*)d_out;

    // ---- ws layout (all chunks 16B-aligned) ----
    char* ws = (char*)d_ws;
    int*   inv    = (int*)ws;                                ws += (size_t)N_F * 4;
    float* h_a    = (float*)ws;                              ws += (size_t)NB * N_C * 64 * 4;
    int*   cnt    = (int*)ws;                                ws += (size_t)(N_F + N_C) * 4;
    int*   cursor = (int*)ws;                                ws += (size_t)(N_F + N_C) * 4;
    int*   csum   = (int*)ws;                                ws += 320 * 4;
    int*   cbase  = (int*)ws;                                ws += 320 * 4;   // unused (layout stability)
    i32x4* ef_info = (i32x4*)ws;                             ws += (size_t)E_F * 16;
    i32x4* ec_info = (i32x4*)ws;                             ws += (size_t)E_C * 16;
    _Float16* sW1n = (_Float16*)ws;                          ws += (size_t)128 * 256 * 2;
    _Float16* sW2s = (_Float16*)ws;                          ws += (size_t)128 * 128 * 2;
    _Float16* aW1n = (_Float16*)ws;                          ws += (size_t)128 * 128 * 2;
    _Float16* aW2s = (_Float16*)ws;                          ws += (size_t)64 * 64 * 2;
    _Float16* bW1n = (_Float16*)ws;                          ws += (size_t)64 * 256 * 2;
    _Float16* bW2s = (_Float16*)ws;                          ws += (size_t)128 * 128 * 2;
    _Float16* b1h  = (_Float16*)ws;                          ws += 1024;   // 320 halfs, padded
    unsigned char* flagF = (unsigned char*)ws;               ws += (size_t)N_F;
    _Float16* P_s  = (_Float16*)ws;                          ws += (size_t)NB * N_C * 256 * 2;
    _Float16* P_a  = (_Float16*)ws;                          ws += (size_t)NB * N_C * 128 * 2;
    _Float16* P_b  = (_Float16*)ws;                          ws += (size_t)NB * N_C * 256 * 2;
    (void)cbase;

    // 1) clear inv + cnt
    clear_small<<<(int)((INV4 + CNT4 + 255) / 256), 256, 0, stream>>>(inv, cnt);

    // 2) setup: build_inv + weight swizzles + b1h + both histograms
    setup_all<<<1746, 256, 0, stream>>>(idx, inv, sW1, sW2, aW1, aW2, bW1, bW2,
                                        sb1, ab1, bb1,
                                        sW1n, sW2s, aW1n, aW2s, bW1n, bW2s, b1h,
                                        ei_f, ei_c, cnt);

    // 3) per-block sums
    scan1<<<320, 256, 0, stream>>>(cnt, csum);

    // 4) per-bin starts (inline base) + selective zero/flag
    scan3zf<<<320, 256, 0, stream>>>(cnt, csum, cursor, flagF, out, h_a);

    // 5) merged: edge scatter (+resolved einfo) and s/a node projections
    scatter_nodesa<<<1280 + 2 * (NB * N_C / 64), 256, 0, stream>>>(
        ei_f, ei_c, inv, cursor, ef_info, ec_info,
        x, sW1n, sb1, P_s, aW1n, ab1, P_a);

    // 6) stage 8: h_a = edgeconv(x, ei_c, a-params)
    edge2_mfma<64, true><<<NB * E_C / 64, 256, 0, stream>>>(
        P_a, N_C * 128, ec_info, E_C, aW2s, ab2, ag, abt, b1h + 128, h_a, N_C * 64);

    // 7) node projection for b conv (from h_a)
    node_gemm<64, 128><<<NB * N_C / 64, 256, 0, stream>>>(h_a, bW1n, bb1, P_b);

    // 8) stages 7+9 fused, 2-tile pipelined: out = leaky(LN_s + LN_b) per dst
    edge2_dual<<<NB * E_F / 128, 256, 0, stream>>>(
        P_s, P_b, ef_info,
        sW2s, sb2, sg, sbt,
        bW2s, bb2, bg, bbt,
        b1h, b1h + 192, out);

    // 9) leaky for flagged rows
    leaky_fix<<<(int)(((size_t)NB * N_F * 32 + 255) / 256), 256, 0, stream>>>(out, flagF);
}

// Round 10
// 274.269 us; speedup vs baseline: 1.3905x; 1.3905x over previous
//
#include <hip/hip_runtime.h>

typedef _Float16 half8  __attribute__((ext_vector_type(8)));
typedef _Float16 half4v __attribute__((ext_vector_type(4)));
typedef _Float16 half2v __attribute__((ext_vector_type(2)));
typedef float    f32x4  __attribute__((ext_vector_type(4)));
typedef float    f32x2  __attribute__((ext_vector_type(2)));
typedef int      i32x4  __attribute__((ext_vector_type(4)));

#define NB 2
#define N_C 16384
#define N_F 65536
#define E_C 65536
#define E_F 262144

#define INV4  ((size_t)N_F / 4)                    // 16,384
#define CNT4  ((size_t)(N_F + N_C) / 4)            // 20,480

// ---------------- small clear: inv=-1, cnt=0 ----------------
__global__ void clear_small(int* __restrict__ inv, int* __restrict__ cnt) {
    size_t i = (size_t)blockIdx.x * 256 + threadIdx.x;
    const i32x4 z = {0, 0, 0, 0};
    const i32x4 m1 = {-1, -1, -1, -1};
    if (i < INV4) ((i32x4*)inv)[i] = m1;
    else if (i < INV4 + CNT4) ((i32x4*)cnt)[i - INV4] = z;
}

// ---------------- weight swizzles ----------------
__device__ inline void swizzle_dev(const float* __restrict__ W, _Float16* __restrict__ Ws,
                                   int N, int o) {
    int j = o & 7;
    int lane = (o >> 3) & 63;
    int frag = o >> 9;
    int ntiles = N >> 4;
    int nt = frag % ntiles;
    int kt = frag / ntiles;
    int k = kt * 32 + (lane >> 4) * 8 + j;
    int n = nt * 16 + (lane & 15);
    Ws[o] = (_Float16)W[k * N + n];
}

__device__ inline void swz_node(const float* __restrict__ W, _Float16* __restrict__ Ws,
                                int CIN, int COUT, int o) {
    int j = o & 7;
    int lane = (o >> 3) & 63;
    int frag = o >> 9;
    int N2 = 2 * COUT;
    int ntiles = N2 >> 4;
    int nt = frag % ntiles;
    int kt = frag / ntiles;
    int k = kt * 32 + (lane >> 4) * 8 + j;
    int n = nt * 16 + (lane & 15);
    float v = (n < COUT) ? W[k * COUT + n] - W[(k + CIN) * COUT + n]
                         : W[(k + CIN) * COUT + (n - COUT)];
    Ws[o] = (_Float16)v;
}

// block ranges: [0,64) inv | [64,192) sW1n | [192,256) sW2 | [256,320) aW1n
//               [320,336) aW2 | [336,400) bW1n | [400,464) bW2 | [464,466) b1h
//               [466,1490) hist_f | [1490,1746) hist_c
__global__ void setup_all(const int* __restrict__ idx, int* __restrict__ inv,
                          const float* sW1, const float* sW2, const float* aW1,
                          const float* aW2, const float* bW1, const float* bW2,
                          const float* sb1, const float* ab1, const float* bb1,
                          _Float16* sW1n, _Float16* sW2s, _Float16* aW1n,
                          _Float16* aW2s, _Float16* bW1n, _Float16* bW2s,
                          _Float16* b1h,
                          const int* __restrict__ ei_f, const int* __restrict__ ei_c,
                          int* __restrict__ cnt) {
    const int bb = blockIdx.x, t = threadIdx.x;
    if (bb < 64) {
        int i = bb * 256 + t;
        inv[idx[i]] = i;
    } else if (bb < 192) {
        swz_node(sW1, sW1n, 128, 128, (bb - 64) * 256 + t);
    } else if (bb < 256) {
        swizzle_dev(sW2, sW2s, 128, (bb - 192) * 256 + t);
    } else if (bb < 320) {
        swz_node(aW1, aW1n, 128, 64, (bb - 256) * 256 + t);
    } else if (bb < 336) {
        swizzle_dev(aW2, aW2s, 64, (bb - 320) * 256 + t);
    } else if (bb < 400) {
        swz_node(bW1, bW1n, 64, 128, (bb - 336) * 256 + t);
    } else if (bb < 464) {
        swizzle_dev(bW2, bW2s, 128, (bb - 400) * 256 + t);
    } else if (bb < 466) {
        int i = (bb - 464) * 256 + t;
        if (i < 128) b1h[i] = (_Float16)sb1[i];
        else if (i < 192) b1h[i] = (_Float16)ab1[i - 128];
        else if (i < 320) b1h[i] = (_Float16)bb1[i - 192];
    } else if (bb < 1490) {
        int e = (bb - 466) * 256 + t;
        atomicAdd(&cnt[ei_f[E_F + e]], 1);
    } else {
        int e = (bb - 1490) * 256 + t;
        atomicAdd(&cnt[N_F + ei_c[E_C + e]], 1);
    }
}

// ---------------- counting sort ----------------
__global__ void scan1(const int* __restrict__ cnt, int* __restrict__ csum) {
    __shared__ int red[4];
    int v = cnt[blockIdx.x * 256 + threadIdx.x];
    #pragma unroll
    for (int off = 32; off >= 1; off >>= 1) v += __shfl_xor(v, off, 64);
    if ((threadIdx.x & 63) == 0) red[threadIdx.x >> 6] = v;
    __syncthreads();
    if (threadIdx.x == 0) csum[blockIdx.x] = red[0] + red[1] + red[2] + red[3];
}

// scan3 + inline block-base (replaces scan2) + selective zero + flag
// f-rows: 32-aligned windows (dual scatters in 32-row windows)
// c-rows: 16-aligned windows (COUT=64 kernel)
__global__ void scan3zf(const int* __restrict__ cnt, const int* __restrict__ csum,
                        int* __restrict__ cursor, unsigned char* __restrict__ flagF,
                        float* __restrict__ out, float* __restrict__ h_a) {
    __shared__ int buf[256];
    __shared__ int red[4];
    const int t = threadIdx.x, bb = blockIdx.x;

    const int lo = (bb < 256) ? 0 : 256;
    int part = 0;
    for (int j = lo + t; j < bb; j += 256) part += csum[j];
    #pragma unroll
    for (int off = 32; off >= 1; off >>= 1) part += __shfl_xor(part, off, 64);
    if ((t & 63) == 0) red[t >> 6] = part;

    const int d = bb * 256 + t;
    int v = cnt[d];
    buf[t] = v;
    __syncthreads();
    const int base = red[0] + red[1] + red[2] + red[3];
    for (int off = 1; off < 256; off <<= 1) {
        int u = (t >= off) ? buf[t - off] : 0;
        __syncthreads();
        buf[t] += u;
        __syncthreads();
    }
    const int start = base + buf[t] - v;
    cursor[d] = start;
    const int deg = v;
    const int end = start + deg;
    const f32x4 z = {0.f, 0.f, 0.f, 0.f};
    if (d < N_F) {
        const bool pred = (deg == 0) || ((start >> 5) != ((end - 1) >> 5));
        flagF[d] = pred ? 1 : 0;
        if (pred) {
            f32x4* r0 = (f32x4*)(out + (size_t)d * 128);
            f32x4* r1 = (f32x4*)(out + ((size_t)N_F + d) * 128);
            #pragma unroll
            for (int i = 0; i < 32; ++i) { r0[i] = z; r1[i] = z; }
        }
    } else {
        const int dc = d - N_F;
        const bool pred = (deg == 0) || ((start >> 4) != ((end - 1) >> 4));
        if (pred) {
            f32x4* r0 = (f32x4*)(h_a + (size_t)dc * 64);
            f32x4* r1 = (f32x4*)(h_a + ((size_t)N_C + dc) * 64);
            #pragma unroll
            for (int i = 0; i < 16; ++i) { r0[i] = z; r1[i] = z; }
        }
    }
}

// ---------------- node-level GEMM1 body: P[node] = [ x@(W1t-W1b)+b1 | x@W1b ] (fp16) ----------------
template <int CIN, int COUT>
__device__ void node_gemm_body(const float* __restrict__ x, const _Float16* __restrict__ W1n,
                               const float* __restrict__ b1, _Float16* __restrict__ P,
                               _Float16* L, int blk, int t) {
    constexpr int N2 = 2 * COUT;
    constexpr int FP = CIN + 8;
    constexpr int P2 = N2 + 8;
    constexpr int NPW = N2 / 4;
    constexpr int NT = NPW / 16;

    const size_t r0 = (size_t)blk * 64;

    {
        const int m = t >> 2, l4 = t & 3;
        const float* src = x + (r0 + m) * CIN + l4 * (CIN / 4);
        #pragma unroll
        for (int i = 0; i < CIN / 16; ++i) {
            f32x4 v = *(const f32x4*)(src + i * 4);
            half4v h;
            #pragma unroll
            for (int c = 0; c < 4; ++c) h[c] = (_Float16)v[c];
            *(half4v*)(L + m * FP + l4 * (CIN / 4) + i * 4) = h;
        }
    }
    __syncthreads();

    const int wv = t >> 6, lane = t & 63;
    const int q = lane >> 4, lm = lane & 15;
    const int n0 = wv * NPW;
    const f32x4 zero4 = {0.f, 0.f, 0.f, 0.f};

    f32x4 acc[4][NT];
    #pragma unroll
    for (int mt = 0; mt < 4; ++mt)
        #pragma unroll
        for (int nt = 0; nt < NT; ++nt) acc[mt][nt] = zero4;

    __builtin_amdgcn_s_setprio(1);
    #pragma unroll
    for (int kt = 0; kt < CIN / 32; ++kt) {
        half8 a[4];
        #pragma unroll
        for (int mt = 0; mt < 4; ++mt)
            a[mt] = *(const half8*)(L + (mt * 16 + lm) * FP + kt * 32 + q * 8);
        #pragma unroll
        for (int nt = 0; nt < NT; ++nt) {
            half8 bf = *(const half8*)(W1n + ((size_t)(kt * (N2 / 16) + wv * NT + nt) * 64 + lane) * 8);
            #pragma unroll
            for (int mt = 0; mt < 4; ++mt)
                acc[mt][nt] = __builtin_amdgcn_mfma_f32_16x16x32_f16(a[mt], bf, acc[mt][nt], 0, 0, 0);
        }
    }
    __builtin_amdgcn_s_setprio(0);
    __syncthreads();

    #pragma unroll
    for (int nt = 0; nt < NT; ++nt) {
        const int col = n0 + nt * 16 + lm;
        const float bv = (col < COUT) ? b1[col] : 0.f;
        #pragma unroll
        for (int mt = 0; mt < 4; ++mt)
            #pragma unroll
            for (int r = 0; r < 4; ++r)
                L[(mt * 16 + q * 4 + r) * P2 + col] = (_Float16)(acc[mt][nt][r] + bv);
    }
    __syncthreads();

    constexpr int CH = 64 * N2 / 8;
    for (int i = t; i < CH; i += 256) {
        int row = i / (N2 / 8), c8 = i % (N2 / 8);
        *(half8*)(P + (r0 + row) * N2 + c8 * 8) = *(const half8*)(L + row * P2 + c8 * 8);
    }
}

// ---------------- merged: edge scatter (+einfo) and s/a node GEMMs ----------------
__launch_bounds__(256, 4) __global__
void scatter_nodesa(const int* __restrict__ ei_f, const int* __restrict__ ei_c,
                    const int* __restrict__ inv, int* __restrict__ cursor,
                    i32x4* __restrict__ ef_info, i32x4* __restrict__ ec_info,
                    const float* __restrict__ x,
                    const _Float16* __restrict__ sW1n, const float* __restrict__ sb1,
                    _Float16* __restrict__ Ps,
                    const _Float16* __restrict__ aW1n, const float* __restrict__ ab1,
                    _Float16* __restrict__ Pa) {
    __shared__ __align__(16) _Float16 L[16896];
    const int bb = blockIdx.x, t = threadIdx.x;
    if (bb < 1024) {
        int e = bb * 256 + t;
        int s_ = ei_f[e];
        int d_ = ei_f[E_F + e];
        int p = atomicAdd(&cursor[d_], 1);
        i32x4 rec;
        rec.x = inv[s_]; rec.y = inv[d_]; rec.z = d_; rec.w = 0;
        ef_info[p] = rec;
    } else if (bb < 1280) {
        int e = (bb - 1024) * 256 + t;
        int s_ = ei_c[e];
        int d_ = ei_c[E_C + e];
        int p = atomicAdd(&cursor[N_F + d_], 1);
        i32x4 rec;
        rec.x = s_; rec.y = d_; rec.z = d_; rec.w = 0;
        ec_info[p] = rec;
    } else if (bb < 1280 + NB * N_C / 64) {
        node_gemm_body<128, 128>(x, sW1n, sb1, Ps, L, bb - 1280, t);
    } else {
        node_gemm_body<128, 64>(x, aW1n, ab1, Pa, L, bb - 1280 - NB * N_C / 64, t);
    }
}

// standalone node GEMM for the b conv (depends on h_a)
template <int CIN, int COUT>
__launch_bounds__(256, 4) __global__
void node_gemm(const float* __restrict__ x, const _Float16* __restrict__ W1n,
               const float* __restrict__ b1, _Float16* __restrict__ P) {
    __shared__ __align__(16) _Float16 L[16896];
    node_gemm_body<CIN, COUT>(x, W1n, b1, P, L, blockIdx.x, threadIdx.x);
}

__device__ inline half8 relu8(half8 h) {
#if __has_builtin(__builtin_elementwise_max)
    half8 z = {};
    return __builtin_elementwise_max(h, z);
#else
    #pragma unroll
    for (int i = 0; i < 8; ++i) h[i] = h[i] > (_Float16)0 ? h[i] : (_Float16)0;
    return h;
#endif
}

// ---------------- single edgeconv (stage 8, COUT=64) ----------------
template <int COUT, bool FRESH>
__launch_bounds__(256, 8) __global__
void edge2_mfma(const _Float16* __restrict__ P, int ps,
                const i32x4* __restrict__ einfo, int E,
                const _Float16* __restrict__ W2s, const float* __restrict__ b2,
                const float* __restrict__ g, const float* __restrict__ bt,
                const _Float16* __restrict__ b1h,
                float* __restrict__ dest, int bs_out) {
    constexpr int HPITCH = COUT + 8;
    constexpr int NPW = COUT / 4;
    constexpr int NT = NPW / 16;

    __shared__ __align__(16) _Float16 region[64 * HPITCH];
    __shared__ int dstl[64];
    __shared__ int dpnL[2];
    __shared__ float muL[64];
    __shared__ float rsL[64];

    _Float16* h1L = region;
    _Float16* vnL = region;

    const int t = threadIdx.x;
    const int eb = blockIdx.x * 64;
    const int b = eb / E;
    const int e0 = eb - b * E;

    {
        if (t == 0) dpnL[0] = (e0 > 0) ? einfo[e0 - 1].z : -2;
        else if (t == 1) dpnL[1] = (e0 + 64 < E) ? einfo[e0 + 64].z : -2;
        const int m = t >> 2, l4 = t & 3;
        const i32x4 rec = einfo[e0 + m];
        const int si = rec.x, di = rec.y;
        if (l4 == 0) dstl[m] = rec.z;
        const _Float16* pb = P + (size_t)b * ps;
        const _Float16* ub = (di >= 0) ? pb + (size_t)di * (2 * COUT) : b1h;
        const _Float16* vb = pb + (size_t)(si >= 0 ? si : 0) * (2 * COUT) + COUT;
        constexpr int CPT = COUT / 4;
        const int c0 = l4 * CPT;
        #pragma unroll
        for (int i = 0; i < CPT / 8; ++i) {
            half8 u = *(const half8*)(ub + c0 + i * 8);
            half8 v = {};
            if (si >= 0) v = *(const half8*)(vb + c0 + i * 8);
            *(half8*)(h1L + m * HPITCH + c0 + i * 8) = relu8(u + v);
        }
    }
    __syncthreads();  // B1

    const int wv = t >> 6, lane = t & 63;
    const int q = lane >> 4, lm = lane & 15;
    const int n0 = wv * NPW;
    const f32x4 zero4 = {0.f, 0.f, 0.f, 0.f};

    f32x4 acc[4][NT];
    #pragma unroll
    for (int mt = 0; mt < 4; ++mt)
        #pragma unroll
        for (int nt = 0; nt < NT; ++nt) acc[mt][nt] = zero4;

    __builtin_amdgcn_s_setprio(1);
    #pragma unroll
    for (int kt = 0; kt < COUT / 32; ++kt) {
        half8 a[4];
        #pragma unroll
        for (int mt = 0; mt < 4; ++mt)
            a[mt] = *(const half8*)(h1L + (mt * 16 + lm) * HPITCH + kt * 32 + q * 8);
        #pragma unroll
        for (int nt = 0; nt < NT; ++nt) {
            half8 bf = *(const half8*)(W2s + ((size_t)(kt * (COUT / 16) + wv * NT + nt) * 64 + lane) * 8);
            #pragma unroll
            for (int mt = 0; mt < 4; ++mt)
                acc[mt][nt] = __builtin_amdgcn_mfma_f32_16x16x32_f16(a[mt], bf, acc[mt][nt], 0, 0, 0);
        }
    }
    __builtin_amdgcn_s_setprio(0);
    __syncthreads();  // B2

    #pragma unroll
    for (int nt = 0; nt < NT; ++nt) {
        const float b2v = b2[n0 + nt * 16 + lm];
        #pragma unroll
        for (int mt = 0; mt < 4; ++mt)
            #pragma unroll
            for (int r = 0; r < 4; ++r)
                vnL[(mt * 16 + q * 4 + r) * HPITCH + n0 + nt * 16 + lm] =
                    (_Float16)(acc[mt][nt][r] + b2v);
    }
    __syncthreads();  // B3

    {
        const int m = t >> 2, p = t & 3;
        constexpr int CPT = COUT / 4;
        float s = 0.f, s2 = 0.f;
        #pragma unroll
        for (int c = 0; c < CPT / 8; ++c) {
            half8 h8 = *(const half8*)(vnL + m * HPITCH + p * CPT + c * 8);
            #pragma unroll
            for (int j = 0; j < 8; ++j) {
                float v = (float)h8[j];
                s += v;
                s2 += v * v;
            }
        }
        s += __shfl_xor(s, 1, 64);  s2 += __shfl_xor(s2, 1, 64);
        s += __shfl_xor(s, 2, 64);  s2 += __shfl_xor(s2, 2, 64);
        if (p == 0) {
            float mu = s * (1.f / COUT);
            muL[m] = mu;
            rsL[m] = rsqrtf(s2 * (1.f / COUT) - mu * mu + 1e-5f);
        }
    }
    __syncthreads();  // B4

    {
        constexpr int CG = COUT / 64;
        constexpr int W  = 4 / CG;
        constexpr int RW = 64 / W;
        const int wv2 = t >> 6, l2 = t & 63;
        const int cg = wv2 % CG;
        const int h  = wv2 / CG;
        const int c  = cg * 64 + l2;
        const int r0 = h * RW;
        const float gv = g[c], bv = bt[c];
        float* const ob = dest + (size_t)b * bs_out + c;
        int dcur = dstl[r0];
        const int dprev = (r0 == 0) ? dpnL[0] : dstl[r0 - 1];
        bool bflag = (dcur == dprev);
        float rs = 0.f;
        #pragma unroll
        for (int i = 0; i < RW; ++i) {
            const int m = r0 + i;
            const float v = (float)vnL[m * HPITCH + c];
            rs += (v - muL[m]) * rsL[m] * gv + bv;
            const int dnxt = (i == RW - 1)
                               ? ((r0 + RW == 64) ? dpnL[1] : dstl[r0 + RW])
                               : dstl[m + 1];
            if (dnxt != dcur) {
                if (!FRESH || bflag) atomicAdd(ob + (size_t)dcur * COUT, rs);
                else ob[(size_t)dcur * COUT] = rs;
                rs = 0.f; dcur = dnxt; bflag = false;
            } else if (i == RW - 1) {
                atomicAdd(ob + (size_t)dcur * COUT, rs);
            }
        }
    }
}

// ---------------- fused dual edgeconv (stages 7+9, COUT=128, E=E_F) — R5/R7 structure ----------------
__launch_bounds__(256, 4) __global__
void edge2_dual(const _Float16* __restrict__ Ps, const _Float16* __restrict__ Pb,
                const i32x4* __restrict__ einfo,
                const _Float16* __restrict__ W2sS, const float* __restrict__ b2s,
                const float* __restrict__ gS, const float* __restrict__ btS,
                const _Float16* __restrict__ W2sB, const float* __restrict__ b2b,
                const float* __restrict__ gB, const float* __restrict__ btB,
                const _Float16* __restrict__ b1hS, const _Float16* __restrict__ b1hB,
                float* __restrict__ out) {
    constexpr int E = E_F;
    constexpr int HP = 136;   // h1 pitch (halfs)
    constexpr int IP = 264;   // interleaved vn pitch (halfs)

    __shared__ __align__(16) _Float16 region[2 * 64 * HP];
    __shared__ int dstl[64];
    __shared__ int dpn[2];
    __shared__ f32x4 stat4[64];   // {rsS, -muS*rsS, rsB, -muB*rsB}

    _Float16* h1S = region;
    _Float16* h1B = region + 64 * HP;
    _Float16* vnI = region;

    const int t = threadIdx.x;
    const int eb = blockIdx.x * 64;
    const int b = eb / E;
    const int e0 = eb - b * E;

    // ---- gather ----
    {
        if (t == 0) dpn[0] = (e0 > 0) ? einfo[e0 - 1].z : -2;
        else if (t == 1) dpn[1] = (e0 + 64 < E) ? einfo[e0 + 64].z : -2;
        const int m = t >> 2, l4 = t & 3;
        const i32x4 rec = einfo[e0 + m];
        const int si = rec.x, di = rec.y;
        if (l4 == 0) dstl[m] = rec.z;
        const size_t pofs = (size_t)b * ((size_t)N_C * 256);
        const _Float16* ubS = (di >= 0) ? Ps + pofs + (size_t)di * 256 : b1hS;
        const _Float16* ubB = (di >= 0) ? Pb + pofs + (size_t)di * 256 : b1hB;
        const size_t so = (size_t)(si >= 0 ? si : 0) * 256 + 128;
        const _Float16* vbS = Ps + pofs + so;
        const _Float16* vbB = Pb + pofs + so;
        const int c0 = l4 * 32;
        #pragma unroll
        for (int i = 0; i < 4; ++i) {
            half8 uS = *(const half8*)(ubS + c0 + i * 8);
            half8 uB = *(const half8*)(ubB + c0 + i * 8);
            half8 vS = {}, vB = {};
            if (si >= 0) {
                vS = *(const half8*)(vbS + c0 + i * 8);
                vB = *(const half8*)(vbB + c0 + i * 8);
            }
            *(half8*)(h1S + m * HP + c0 + i * 8) = relu8(uS + vS);
            *(half8*)(h1B + m * HP + c0 + i * 8) = relu8(uB + vB);
        }
    }
    __syncthreads();  // B1

    const int wv = t >> 6, lane = t & 63;
    const int q = lane >> 4, lm = lane & 15;
    const int n0 = wv * 32;
    const f32x4 zero4 = {0.f, 0.f, 0.f, 0.f};

    f32x4 accS[4][2], accB[4][2];
    #pragma unroll
    for (int mt = 0; mt < 4; ++mt)
        #pragma unroll
        for (int nt = 0; nt < 2; ++nt) { accS[mt][nt] = zero4; accB[mt][nt] = zero4; }

    // ---- GEMM2 x2 ----
    __builtin_amdgcn_s_setprio(1);
    #pragma unroll
    for (int kt = 0; kt < 4; ++kt) {
        half8 aS[4], aB[4];
        #pragma unroll
        for (int mt = 0; mt < 4; ++mt) {
            aS[mt] = *(const half8*)(h1S + (mt * 16 + lm) * HP + kt * 32 + q * 8);
            aB[mt] = *(const half8*)(h1B + (mt * 16 + lm) * HP + kt * 32 + q * 8);
        }
        #pragma unroll
        for (int nt = 0; nt < 2; ++nt) {
            half8 bS = *(const half8*)(W2sS + ((size_t)(kt * 8 + wv * 2 + nt) * 64 + lane) * 8);
            half8 bB = *(const half8*)(W2sB + ((size_t)(kt * 8 + wv * 2 + nt) * 64 + lane) * 8);
            #pragma unroll
            for (int mt = 0; mt < 4; ++mt) {
                accS[mt][nt] = __builtin_amdgcn_mfma_f32_16x16x32_f16(aS[mt], bS, accS[mt][nt], 0, 0, 0);
                accB[mt][nt] = __builtin_amdgcn_mfma_f32_16x16x32_f16(aB[mt], bB, accB[mt][nt], 0, 0, 0);
            }
        }
    }
    __builtin_amdgcn_s_setprio(0);
    __syncthreads();  // B2

    // ---- vn write, interleaved [row][col][S,B] ----
    #pragma unroll
    for (int nt = 0; nt < 2; ++nt) {
        const int col = n0 + nt * 16 + lm;
        const float b2vS = b2s[col];
        const float b2vB = b2b[col];
        #pragma unroll
        for (int mt = 0; mt < 4; ++mt)
            #pragma unroll
            for (int r = 0; r < 4; ++r) {
                const int row = mt * 16 + q * 4 + r;
                half2v pk;
                pk[0] = (_Float16)(accS[mt][nt][r] + b2vS);
                pk[1] = (_Float16)(accB[mt][nt][r] + b2vB);
                *(half2v*)(vnI + row * IP + col * 2) = pk;
            }
    }
    __syncthreads();  // B3

    // ---- LN stats (both convs) ----
    {
        const int m = t >> 2, p = t & 3;
        float sS = 0.f, s2S = 0.f, sB = 0.f, s2B = 0.f;
        #pragma unroll
        for (int k = 0; k < 8; ++k) {
            half8 h8 = *(const half8*)(vnI + m * IP + p * 64 + k * 8);
            #pragma unroll
            for (int j = 0; j < 8; j += 2) {
                float a = (float)h8[j];     sS += a; s2S += a * a;
                float c = (float)h8[j + 1]; sB += c; s2B += c * c;
            }
        }
        sS += __shfl_xor(sS, 1, 64);  s2S += __shfl_xor(s2S, 1, 64);
        sS += __shfl_xor(sS, 2, 64);  s2S += __shfl_xor(s2S, 2, 64);
        sB += __shfl_xor(sB, 1, 64);  s2B += __shfl_xor(s2B, 1, 64);
        sB += __shfl_xor(sB, 2, 64);  s2B += __shfl_xor(s2B, 2, 64);
        if (p == 0) {
            const float mS = sS * (1.f / 128.f);
            const float rS = rsqrtf(s2S * (1.f / 128.f) - mS * mS + 1e-5f);
            const float mB = sB * (1.f / 128.f);
            const float rB = rsqrtf(s2B * (1.f / 128.f) - mB * mB + 1e-5f);
            f32x4 st;
            st[0] = rS; st[1] = -mS * rS; st[2] = rB; st[3] = -mB * rB;
            stat4[m] = st;
        }
    }
    __syncthreads();  // B4

    // ---- combined LN apply + run-aggregated store ----
    {
        const int wv2 = t >> 6, l2 = t & 63;
        const int cg = wv2 & 1;
        const int h  = wv2 >> 1;
        const int c  = cg * 64 + l2;
        const int r0 = h * 32;
        const float gS_ = gS[c], gB_ = gB[c];
        const float bsum = btS[c] + btB[c];
        float* const ob = out + (size_t)b * ((size_t)N_F * 128) + c;
        int dcur = dstl[r0];
        const int dprev = (r0 == 0) ? dpn[0] : dstl[r0 - 1];
        bool bflag = (dcur == dprev);
        float rs = 0.f;
        #pragma unroll
        for (int i = 0; i < 32; ++i) {
            const int m = r0 + i;
            const half2v v2 = *(const half2v*)(vnI + m * IP + c * 2);
            const f32x4 st = stat4[m];
            rs += fmaf((float)v2[0], st[0], st[1]) * gS_
                + fmaf((float)v2[1], st[2], st[3]) * gB_ + bsum;
            const int dnxt = (i == 31)
                               ? ((r0 + 32 == 64) ? dpn[1] : dstl[r0 + 32])
                               : dstl[m + 1];
            if (dnxt != dcur) {
                if (bflag) {
                    atomicAdd(ob + (size_t)dcur * 128, rs);
                } else {
                    float v = rs > 0.f ? rs : 0.01f * rs;  // leaky: single writer
                    ob[(size_t)dcur * 128] = v;
                }
                rs = 0.f; dcur = dnxt; bflag = false;
            } else if (i == 31) {
                atomicAdd(ob + (size_t)dcur * 128, rs);
            }
        }
    }
}

// ---------------- fixup: leaky for flagged rows only ----------------
__global__ void leaky_fix(float* __restrict__ out, const unsigned char* __restrict__ flagF) {
    const size_t i = (size_t)blockIdx.x * 256 + threadIdx.x;
    if (i >= (size_t)NB * N_F * 32) return;
    const int d = (int)((i >> 5) & (N_F - 1));
    if (!flagF[d]) return;
    f32x4 v = ((f32x4*)out)[i];
    #pragma unroll
    for (int c = 0; c < 4; ++c) v[c] = v[c] > 0.f ? v[c] : 0.01f * v[c];
    ((f32x4*)out)[i] = v;
}

extern "C" void kernel_launch(void* const* d_in, const int* in_sizes, int n_in,
                              void* d_out, int out_size, void* d_ws, size_t ws_size,
                              hipStream_t stream) {
    const float* x    = (const float*)d_in[0];
    const int*   idx  = (const int*)d_in[1];
    const int*   ei_c = (const int*)d_in[2];
    const int*   ei_f = (const int*)d_in[3];
    const float* sW1 = (const float*)d_in[4];
    const float* sb1 = (const float*)d_in[5];
    const float* sW2 = (const float*)d_in[6];
    const float* sb2 = (const float*)d_in[7];
    const float* sg  = (const float*)d_in[8];
    const float* sbt = (const float*)d_in[9];
    const float* aW1 = (const float*)d_in[10];
    const float* ab1 = (const float*)d_in[11];
    const float* aW2 = (const float*)d_in[12];
    const float* ab2 = (const float*)d_in[13];
    const float* ag  = (const float*)d_in[14];
    const float* abt = (const float*)d_in[15];
    const float* bW1 = (const float*)d_in[16];
    const float* bb1 = (const float*)d_in[17];
    const float* bW2 = (const float*)d_in[18];
    const float* bb2 = (const float*)d_in[19];
    const float* bg  = (const float*)d_in[20];
    const float* bbt = (const float*)d_in[21];

    float* out = (float*)d_out;

    // ---- ws layout (all chunks 16B-aligned) ----
    char* ws = (char*)d_ws;
    int*   inv    = (int*)ws;                                ws += (size_t)N_F * 4;
    float* h_a    = (float*)ws;                              ws += (size_t)NB * N_C * 64 * 4;
    int*   cnt    = (int*)ws;                                ws += (size_t)(N_F + N_C) * 4;
    int*   cursor = (int*)ws;                                ws += (size_t)(N_F + N_C) * 4;
    int*   csum   = (int*)ws;                                ws += 320 * 4;
    int*   cbase  = (int*)ws;                                ws += 320 * 4;   // unused (layout stability)
    i32x4* ef_info = (i32x4*)ws;                             ws += (size_t)E_F * 16;
    i32x4* ec_info = (i32x4*)ws;                             ws += (size_t)E_C * 16;
    _Float16* sW1n = (_Float16*)ws;                          ws += (size_t)128 * 256 * 2;
    _Float16* sW2s = (_Float16*)ws;                          ws += (size_t)128 * 128 * 2;
    _Float16* aW1n = (_Float16*)ws;                          ws += (size_t)128 * 128 * 2;
    _Float16* aW2s = (_Float16*)ws;                          ws += (size_t)64 * 64 * 2;
    _Float16* bW1n = (_Float16*)ws;                          ws += (size_t)64 * 256 * 2;
    _Float16* bW2s = (_Float16*)ws;                          ws += (size_t)128 * 128 * 2;
    _Float16* b1h  = (_Float16*)ws;                          ws += 1024;   // 320 halfs, padded
    unsigned char* flagF = (unsigned char*)ws;               ws += (size_t)N_F;
    _Float16* P_s  = (_Float16*)ws;                          ws += (size_t)NB * N_C * 256 * 2;
    _Float16* P_a  = (_Float16*)ws;                          ws += (size_t)NB * N_C * 128 * 2;
    _Float16* P_b  = (_Float16*)ws;                          ws += (size_t)NB * N_C * 256 * 2;
    (void)cbase;

    // 1) clear inv + cnt
    clear_small<<<(int)((INV4 + CNT4 + 255) / 256), 256, 0, stream>>>(inv, cnt);

    // 2) setup: build_inv + weight swizzles + b1h + both histograms
    setup_all<<<1746, 256, 0, stream>>>(idx, inv, sW1, sW2, aW1, aW2, bW1, bW2,
                                        sb1, ab1, bb1,
                                        sW1n, sW2s, aW1n, aW2s, bW1n, bW2s, b1h,
                                        ei_f, ei_c, cnt);

    // 3) per-block sums
    scan1<<<320, 256, 0, stream>>>(cnt, csum);

    // 4) per-bin starts (inline base) + selective zero/flag
    scan3zf<<<320, 256, 0, stream>>>(cnt, csum, cursor, flagF, out, h_a);

    // 5) merged: edge scatter (+resolved einfo) and s/a node projections
    scatter_nodesa<<<1280 + 2 * (NB * N_C / 64), 256, 0, stream>>>(
        ei_f, ei_c, inv, cursor, ef_info, ec_info,
        x, sW1n, sb1, P_s, aW1n, ab1, P_a);

    // 6) stage 8: h_a = edgeconv(x, ei_c, a-params)
    edge2_mfma<64, true><<<NB * E_C / 64, 256, 0, stream>>>(
        P_a, N_C * 128, ec_info, E_C, aW2s, ab2, ag, abt, b1h + 128, h_a, N_C * 64);

    // 7) node projection for b conv (from h_a)
    node_gemm<64, 128><<<NB * N_C / 64, 256, 0, stream>>>(h_a, bW1n, bb1, P_b);

    // 8) stages 7+9 fused: out = leaky(LN_s(conv_s) + LN_b(conv_b)) per dst
    edge2_dual<<<NB * E_F / 64, 256, 0, stream>>>(
        P_s, P_b, ef_info,
        sW2s, sb2, sg, sbt,
        bW2s, bb2, bg, bbt,
        b1h, b1h + 192, out);

    // 9) leaky for flagged rows
    leaky_fix<<<(int)(((size_t)NB * N_F * 32 + 255) / 256), 256, 0, stream>>>(out, flagF);
}